// Round 6
// baseline (527.866 us; speedup 1.0000x reference)
//
#include <hip/hip_runtime.h>
#include <math.h>

#define N_ROWS 8192
#define DIMS   1024
#define NCLS   512
#define BK     32
#define NT     (DIMS / BK)          // 32 k-tiles
#define NP     32                   // 8192/256 row-blocks
#define NQ     64                   // 8192/128 col-blocks
#define NWG2   1056                 // sum_p (64-2p) triangular 256x128 tiles
#define STAGEBYTES 49152            // Ah16K + Al16K + Bh8K + Bl8K
#define CA     14                   // class rows staged per LDS chunk (56 KB)

typedef __attribute__((ext_vector_type(8))) short bf16x8;
typedef __attribute__((ext_vector_type(4))) float f32x4;
typedef unsigned long long ull;

// ---------- helpers ----------
__device__ __forceinline__ unsigned short f2bf(float f) {
    unsigned u = __float_as_uint(f);
    u += 0x7FFFu + ((u >> 16) & 1u);   // RNE
    return (unsigned short)(u >> 16);
}
__device__ __forceinline__ float bf2f(unsigned short h) {
    return __uint_as_float(((unsigned)h) << 16);
}
// monotone float<->uint for atomic min/max
__device__ __forceinline__ unsigned enc_f(float x) {
    unsigned u = __float_as_uint(x);
    return (u & 0x80000000u) ? ~u : (u | 0x80000000u);
}
__device__ __forceinline__ float dec_f(unsigned u) {
    return (u & 0x80000000u) ? __uint_as_float(u ^ 0x80000000u) : __uint_as_float(~u);
}

__device__ __forceinline__ float dot1024(const float* __restrict__ xi,
                                         const float* __restrict__ xj) {
    const float4* u4 = (const float4*)xi;
    const float4* v4 = (const float4*)xj;
    float a0 = 0.f, a1 = 0.f, a2 = 0.f, a3 = 0.f;
#pragma unroll 8
    for (int q = 0; q < DIMS / 4; ++q) {
        float4 u = u4[q], v = v4[q];
        a0 += u.x * v.x; a1 += u.y * v.y;
        a2 += u.z * v.z; a3 += u.w * v.w;
    }
    return (a0 + a1) + (a2 + a3);
}

typedef __attribute__((address_space(1))) const void* as1_cvp;
typedef __attribute__((address_space(3))) void* as3_vp;
__device__ __forceinline__ void gl_lds16(const void* g, void* l) {
    __builtin_amdgcn_global_load_lds((as1_cvp)g, (as3_vp)l, 16, 0, 0);
}

template <int VMC>
__device__ __forceinline__ void wait_vm() {
    if constexpr (VMC == 12)     asm volatile("s_waitcnt vmcnt(12)" ::: "memory");
    else if constexpr (VMC == 6) asm volatile("s_waitcnt vmcnt(6)" ::: "memory");
    else                         asm volatile("s_waitcnt vmcnt(0)" ::: "memory");
}

// ---------- init (row accumulators only) ----------
__global__ void init_k(int* an_cnt, float* neg_sum, ull* maxneg) {
    int i = blockIdx.x * 256 + threadIdx.x;
    if (i < N_ROWS) {
        an_cnt[i] = 0; neg_sum[i] = 0.f;
        maxneg[i] = ((ull)enc_f(-1e9f)) << 32;
    }
}

// ---------- single-block bucketing: dtype detect + conv + count + scan + scatter ----------
__global__ __launch_bounds__(1024) void bucket_k(const int* __restrict__ raw,
                                                 int* __restrict__ tgt,
                                                 int* __restrict__ cnt,
                                                 int* __restrict__ offs,
                                                 int* __restrict__ pairoff,
                                                 int* __restrict__ members,
                                                 int simcap) {
    __shared__ int sflag;
    __shared__ int scnt[NCLS], soff[NCLS], spair[NCLS], scur[NCLS];
    __shared__ int schunk[16], schunkp[16];
    int tid = threadIdx.x;
    if (tid == 0) sflag = 0;
    for (int c = tid; c < NCLS; c += 1024) scnt[c] = 0;
    __syncthreads();
    int any = 0;
    for (int i = tid; i < N_ROWS / 2; i += 1024) any |= raw[2 * i + 1];
    if (any) atomicOr(&sflag, 1);
    __syncthreads();
    int is32 = sflag;     // nonzero odd 32-bit words => targets are int32
    for (int i = tid; i < N_ROWS; i += 1024) {
        int t = is32 ? raw[i] : raw[2 * i];
        tgt[i] = t;
        if ((unsigned)t < NCLS) atomicAdd(&scnt[t], 1);
    }
    __syncthreads();
    if (tid < 16) {
        int s = 0, sp = 0;
        for (int c = tid * 32; c < tid * 32 + 32; ++c) {
            int k = scnt[c]; int kk = k < 256 ? k : 256;
            s += k; sp += kk * kk;
        }
        schunk[tid] = s; schunkp[tid] = sp;
    }
    __syncthreads();
    if (tid == 0) {
        int s = 0, sp = 0;
        for (int t = 0; t < 16; ++t) {
            int a = schunk[t], b = schunkp[t];
            schunk[t] = s; schunkp[t] = sp;
            s += a; sp += b;
        }
    }
    __syncthreads();
    if (tid < 16) {
        int s = schunk[tid], sp = schunkp[tid];
        for (int c = tid * 32; c < tid * 32 + 32; ++c) {
            int k = scnt[c]; int kk = k < 256 ? k : 256;
            soff[c] = s; scur[c] = s;
            spair[c] = (simcap > 0 && sp + kk * kk <= simcap) ? sp : -1;
            s += k; sp += kk * kk;
        }
    }
    __syncthreads();
    for (int i = tid; i < N_ROWS; i += 1024) {
        int t = tgt[i];
        if ((unsigned)t < NCLS) {
            int p = atomicAdd(&scur[t], 1);
            members[p] = i;
        }
    }
    for (int c = tid; c < NCLS; c += 1024) {
        cnt[c] = scnt[c]; offs[c] = soff[c]; pairoff[c] = spair[c];
    }
}

// ---------- fp32 -> bf16 hi/lo split + row sum of squares (wave per row) ----------
__global__ __launch_bounds__(256) void prep_k(const float* __restrict__ X,
                                              short* __restrict__ Xhi,
                                              short* __restrict__ Xlo,
                                              float* __restrict__ sumsq) {
    int row  = blockIdx.x * 4 + (threadIdx.x >> 6);
    int lane = threadIdx.x & 63;
    const float4* xr = (const float4*)(X + (size_t)row * DIMS);
    short4* oh = (short4*)(Xhi + (size_t)row * DIMS);
    short4* ol = (short4*)(Xlo + (size_t)row * DIMS);
    float ss = 0.f;
#pragma unroll
    for (int t = 0; t < 4; ++t) {
        float4 v = xr[lane + 64 * t];
        ss += v.x * v.x + v.y * v.y + v.z * v.z + v.w * v.w;
        short4 h, l;
        unsigned short hx = f2bf(v.x); h.x = (short)hx; l.x = (short)f2bf(v.x - bf2f(hx));
        unsigned short hy = f2bf(v.y); h.y = (short)hy; l.y = (short)f2bf(v.y - bf2f(hy));
        unsigned short hz = f2bf(v.z); h.z = (short)hz; l.z = (short)f2bf(v.z - bf2f(hz));
        unsigned short hw = f2bf(v.w); h.w = (short)hw; l.w = (short)f2bf(v.w - bf2f(hw));
        oh[lane + 64 * t] = h;
        ol[lane + 64 * t] = l;
    }
#pragma unroll
    for (int off = 1; off < 64; off <<= 1) ss += __shfl_xor(ss, off);
    if (lane == 0) sumsq[row] = ss;
}

// ---------- min_pos: LDS-staged class grams (rows read once, not per pair) ----------
__global__ __launch_bounds__(256) void minpos_k(const float* __restrict__ X,
                                                const int* __restrict__ members,
                                                const int* __restrict__ offs,
                                                const int* __restrict__ cnt,
                                                const int* __restrict__ pairoff,
                                                const float* __restrict__ sumsq,
                                                float* __restrict__ minpos,
                                                float* __restrict__ simbuf) {
    __shared__ __align__(16) float srows[CA][DIMS];   // 56 KB
    __shared__ unsigned smin[256];
    int c = blockIdx.x, tid = threadIdx.x;
    int wave = tid >> 6, lane = tid & 63;
    int k = cnt[c], off = offs[c], spo = pairoff[c];
    smin[tid] = enc_f(1e9f);
    int kk = k < 256 ? k : 256;
    __syncthreads();
    for (int a0 = 0; a0 < kk; a0 += CA) {
        int na = (kk - a0 < CA) ? (kk - a0) : CA;
        // cooperative stage: 256 threads cover one row (256 float4) per step
        for (int idx = tid; idx < na * 256; idx += 256) {
            int r = idx >> 8, c4 = idx & 255;
            int i = members[off + a0 + r];
            ((float4*)&srows[r][0])[c4] = ((const float4*)(X + (size_t)i * DIMS))[c4];
        }
        __syncthreads();
        // wave-per-b: row j in registers, dot vs staged rows from LDS
        for (int b = wave; b < kk; b += 4) {
            int j = members[off + b];
            const float4* xj = (const float4*)(X + (size_t)j * DIMS);
            float4 rj[4];
#pragma unroll
            for (int t = 0; t < 4; ++t) rj[t] = xj[lane + 64 * t];
            for (int a = 0; a < na; ++a) {
                int i = members[off + a0 + a];
                float p0 = 0.f, p1 = 0.f, p2 = 0.f, p3 = 0.f;
#pragma unroll
                for (int t = 0; t < 4; ++t) {
                    float4 u = ((const float4*)&srows[a][0])[lane + 64 * t];
                    p0 += u.x * rj[t].x; p1 += u.y * rj[t].y;
                    p2 += u.z * rj[t].z; p3 += u.w * rj[t].w;
                }
                float s = (p0 + p1) + (p2 + p3);
#pragma unroll
                for (int o = 1; o < 64; o <<= 1) s += __shfl_xor(s, o);
                if (i == j) s = sumsq[i];
                if (lane == 0) {
                    if (spo >= 0) simbuf[spo + (a0 + a) * kk + b] = s;
                    if (s < 1.0f) atomicMin(&smin[a0 + a], enc_f(s));
                }
            }
        }
        __syncthreads();   // srows reuse + smin visibility
    }
    for (int a = tid; a < kk; a += 256) minpos[members[off + a]] = dec_f(smin[a]);
}

// ---------- main fused GEMM: 256x128 tile, 8 waves, 3-deep counted-vmcnt pipeline ----------
#define KSTEP(T, VMC, STG)                                                         \
  {                                                                                \
    wait_vm<VMC>();                                                                \
    __builtin_amdgcn_sched_barrier(0);                                             \
    __builtin_amdgcn_s_barrier();                                                  \
    __builtin_amdgcn_sched_barrier(0);                                             \
    char* base = lds + cur * STAGEBYTES;                                           \
    bf16x8 bh[4], bl[4], ah[4], al[4];                                             \
    _Pragma("unroll")                                                              \
    for (int n = 0; n < 4; ++n) {                                                  \
      int rb = wc * 64 + n * 16 + l15;                                             \
      bh[n] = *(const bf16x8*)(base + 32768 + rb * 64 + l4 * 16);                  \
      bl[n] = *(const bf16x8*)(base + 40960 + rb * 64 + l4 * 16);                  \
    }                                                                              \
    _Pragma("unroll")                                                              \
    for (int m = 0; m < 4; ++m) {                                                  \
      int ra = wr * 64 + m * 16 + l15;                                             \
      ah[m] = *(const bf16x8*)(base + ra * 64 + l4 * 16);                          \
      al[m] = *(const bf16x8*)(base + 16384 + ra * 64 + l4 * 16);                  \
    }                                                                              \
    asm volatile("s_waitcnt lgkmcnt(0)" ::: "memory");                             \
    __builtin_amdgcn_sched_barrier(0);                                             \
    __builtin_amdgcn_s_barrier();                                                  \
    __builtin_amdgcn_sched_barrier(0);                                             \
    if (STG) {                                                                     \
      _Pragma("unroll")                                                            \
      for (int j = 0; j < 6; ++j)                                                  \
        gl_lds16(gptr[j] + (size_t)((T) + 3) * BK, base + ldsu[j]);                \
    }                                                                              \
    __builtin_amdgcn_sched_barrier(0);                                             \
    __builtin_amdgcn_s_setprio(1);                                                 \
    _Pragma("unroll")                                                              \
    for (int m = 0; m < 4; ++m)                                                    \
      _Pragma("unroll")                                                            \
      for (int n = 0; n < 4; ++n) {                                                \
        acc[m][n] = __builtin_amdgcn_mfma_f32_16x16x32_bf16(ah[m], bh[n], acc[m][n], 0, 0, 0); \
        acc[m][n] = __builtin_amdgcn_mfma_f32_16x16x32_bf16(ah[m], bl[n], acc[m][n], 0, 0, 0); \
        acc[m][n] = __builtin_amdgcn_mfma_f32_16x16x32_bf16(al[m], bh[n], acc[m][n], 0, 0, 0); \
      }                                                                            \
    __builtin_amdgcn_s_setprio(0);                                                 \
    cur = (cur == 2) ? 0 : cur + 1;                                                \
  }

__global__ __launch_bounds__(512, 1) void fused_k(const short* __restrict__ Xhi,
                                                  const short* __restrict__ Xlo,
                                                  const int* __restrict__ tgt,
                                                  const float* __restrict__ margin,
                                                  const float* __restrict__ minpos,
                                                  ull* __restrict__ maxneg,
                                                  int* __restrict__ an_cnt,
                                                  float* __restrict__ neg_sum) {
    __shared__ __align__(16) char lds[3 * STAGEBYTES];   // 144 KB

    // bijective XCD-aware swizzle (1056 = 8*132)
    int orig = blockIdx.x;
    int wgid = (orig & 7) * (NWG2 / 8) + (orig >> 3);

    // triangular decode: 256-row block p, 128-col block q, q >= 2p
    int rem = wgid, p = 0;
    while (rem >= NQ - 2 * p) { rem -= NQ - 2 * p; ++p; }
    int q = 2 * p + rem;
    int row0 = p * 256, col0 = q * 128;

    int tid = threadIdx.x, lane = tid & 63, wave = tid >> 6;
    int wr = wave >> 1, wc = wave & 1;          // 4M x 2N wave grid; per-wave out 64x64
    int l15 = lane & 15, l4 = lane >> 4;

    // staging assignment: 48 wave-loads of 1KB; wave w takes u = w + 8j, j=0..5
    const short* gptr[6];
    int ldsu[6];
#pragma unroll
    for (int j = 0; j < 6; ++j) {
        int u = wave + 8 * j;
        const short* s; int baserow, lr;
        if (u < 16)      { s = Xhi; baserow = row0; lr = u * 16; }
        else if (u < 32) { s = Xlo; baserow = row0; lr = (u - 16) * 16; }
        else if (u < 40) { s = Xhi; baserow = col0; lr = (u - 32) * 16; }
        else             { s = Xlo; baserow = col0; lr = (u - 40) * 16; }
        gptr[j] = s + (size_t)(baserow + lr + (lane >> 2)) * DIMS + (lane & 3) * 8;
        ldsu[j] = u * 1024;
    }

    // prologue: stage tiles 0..2
#pragma unroll
    for (int tt = 0; tt < 3; ++tt)
#pragma unroll
        for (int j = 0; j < 6; ++j)
            gl_lds16(gptr[j] + (size_t)tt * BK, lds + tt * STAGEBYTES + ldsu[j]);

    f32x4 acc[4][4] = {};
    int cur = 0;

#pragma unroll 1
    for (int t = 0; t < NT - 3; ++t) KSTEP(t, 12, true);
    KSTEP(NT - 3, 12, false);
    KSTEP(NT - 2, 6, false);
    KSTEP(NT - 1, 0, false);

    // ---- epilogue: C/D layout col=lane&15, row=(lane>>4)*4+r ----
    // per-cell predicate gc > grow: each unordered pair contributes to BOTH
    // endpoints exactly once across the triangular tile cover.
    int tcol[4]; float mcol[4], pcol[4];
#pragma unroll
    for (int n = 0; n < 4; ++n) {
        int gc = col0 + wc * 64 + n * 16 + l15;
        tcol[n] = tgt[gc];
        mcol[n] = margin[gc];
        pcol[n] = minpos[gc];
    }
    ull  cmx[4] = {0, 0, 0, 0};
    float cns[4] = {0, 0, 0, 0};
    int  cct[4] = {0, 0, 0, 0};

#pragma unroll
    for (int m = 0; m < 4; ++m) {
#pragma unroll
        for (int r = 0; r < 4; ++r) {
            int grow = row0 + wr * 64 + m * 16 + l4 * 4 + r;
            int trow = tgt[grow];
            float mg = margin[grow], mp = minpos[grow];
            ull rmx = 0; float rns = 0.f; int rct = 0;
#pragma unroll
            for (int n = 0; n < 4; ++n) {
                float s = acc[m][n][r];
                int gc = col0 + wc * 64 + n * 16 + l15;
                if (trow != tcol[n] && gc > grow) {
                    float e = __expf(10.f * s - 5.f);
                    ull pk = (((ull)enc_f(s)) << 32) | (unsigned)gc;
                    rmx = rmx > pk ? rmx : pk;
                    if (s + mg - mp > 0.f) { rct++; rns += e; }
                    ull pk2 = (((ull)enc_f(s)) << 32) | (unsigned)grow;
                    cmx[n] = cmx[n] > pk2 ? cmx[n] : pk2;
                    if (s + mcol[n] - pcol[n] > 0.f) { cct[n]++; cns[n] += e; }
                }
            }
#pragma unroll
            for (int off = 1; off < 16; off <<= 1) {
                ull o = __shfl_xor(rmx, off); rmx = rmx > o ? rmx : o;
                rns += __shfl_xor(rns, off);
                rct += __shfl_xor(rct, off);
            }
            if (l15 == 0) {
                atomicMax(&maxneg[grow], rmx);
                if (rct) { atomicAdd(&an_cnt[grow], rct); atomicAdd(&neg_sum[grow], rns); }
            }
        }
    }
#pragma unroll
    for (int n = 0; n < 4; ++n) {
#pragma unroll
        for (int off = 16; off < 64; off <<= 1) {
            ull o = __shfl_xor(cmx[n], off); cmx[n] = cmx[n] > o ? cmx[n] : o;
            cns[n] += __shfl_xor(cns[n], off);
            cct[n] += __shfl_xor(cct[n], off);
        }
        if (lane < 16) {
            int gc = col0 + wc * 64 + n * 16 + l15;
            atomicMax(&maxneg[gc], cmx[n]);
            if (cct[n]) { atomicAdd(&an_cnt[gc], cct[n]); atomicAdd(&neg_sum[gc], cns[n]); }
        }
    }
}

// ---------- exact fp32 recompute of max_neg at the GEMM argmax ----------
__global__ __launch_bounds__(256) void repair_k(const float* __restrict__ X,
                                                const ull* __restrict__ maxneg,
                                                float* __restrict__ mn_exact) {
    int row = blockIdx.x * 4 + (threadIdx.x >> 6);
    int lane = threadIdx.x & 63;
    ull p = maxneg[row];
    float outv;
    if ((unsigned)(p >> 32) == enc_f(-1e9f)) {
        outv = -1e9f;
    } else {
        int col = (int)(p & 0xFFFFFFFFu);
        const float4* xi = (const float4*)(X + (size_t)row * DIMS);
        const float4* xj = (const float4*)(X + (size_t)col * DIMS);
        float a0 = 0.f, a1 = 0.f, a2 = 0.f, a3 = 0.f;
#pragma unroll
        for (int t = 0; t < 4; ++t) {
            float4 u = xi[lane + 64 * t], v = xj[lane + 64 * t];
            a0 += u.x * v.x; a1 += u.y * v.y;
            a2 += u.z * v.z; a3 += u.w * v.w;
        }
        float s = (a0 + a1) + (a2 + a3);
#pragma unroll
        for (int off = 1; off < 64; off <<= 1) s += __shfl_xor(s, off);
        outv = s;
    }
    if (lane == 0) mn_exact[row] = outv;
}

// ---------- positive path (reads stored sims) + per-row outputs ----------
__global__ __launch_bounds__(256) void finalize_k(const float* __restrict__ X,
                                                  const int* __restrict__ members,
                                                  const int* __restrict__ offs,
                                                  const int* __restrict__ cnt,
                                                  const int* __restrict__ pairoff,
                                                  const float* __restrict__ simbuf,
                                                  const float* __restrict__ sumsq,
                                                  const float* __restrict__ margin,
                                                  const float* __restrict__ mn_exact,
                                                  const int* __restrict__ an_cnt,
                                                  const float* __restrict__ neg_sum,
                                                  float* __restrict__ out,
                                                  float* __restrict__ loss_c) {
    __shared__ int sap[256];
    __shared__ float sps[256];
    __shared__ float smn[256], smg[256];
    int c = blockIdx.x, tid = threadIdx.x;
    int k = cnt[c], off = offs[c], spo = pairoff[c];
    int kk = k < 256 ? k : 256;
    sap[tid] = 0; sps[tid] = 0.f;
    for (int a = tid; a < kk; a += 256) {
        int i = members[off + a];
        smn[a] = mn_exact[i];
        smg[a] = margin[i];
    }
    __syncthreads();
    for (int p = tid; p < kk * kk; p += 256) {
        int a = p / kk;
        float s;
        if (spo >= 0) {
            s = simbuf[spo + p];
        } else {
            int b = p - a * kk;
            int i = members[off + a], j = members[off + b];
            s = (i == j) ? sumsq[i]
                         : dot1024(X + (size_t)i * DIMS, X + (size_t)j * DIMS);
        }
        if (s < 1.0f && (smn[a] - s + smg[a] > 0.f)) {
            atomicAdd(&sap[a], 1);
            atomicAdd(&sps[a], __expf(-2.f * s + 1.f));
        }
    }
    __syncthreads();
    for (int a = tid; a < kk; a += 256) {
        int i = members[off + a];
        int ap = sap[a];
        int an = an_cnt[i];
        bool valid = (ap > 0) && (an > 0);
        float pl = log1pf(sps[a]);
        float nl = 0.2f * log1pf(neg_sum[i]);
        out[1 + i]              = valid ? 1.f : 0.f;
        out[1 + N_ROWS + i]     = valid ? (float)ap : 0.f;
        out[1 + 2 * N_ROWS + i] = valid ? (float)an : 0.f;
        loss_c[i] = valid ? (pl + nl) : 0.f;
    }
}

// ---------- scalar outputs ----------
__global__ __launch_bounds__(256) void reduce_k(const float* __restrict__ loss_c,
                                                float* __restrict__ out) {
    __shared__ float s1[256], s2[256];
    int tid = threadIdx.x;
    float ls = 0.f, tot = 0.f;
    for (int i = tid; i < N_ROWS; i += 256) {
        ls  += loss_c[i];
        tot += out[1 + N_ROWS + i] + out[1 + 2 * N_ROWS + i];
    }
    s1[tid] = ls; s2[tid] = tot;
    __syncthreads();
    for (int o = 128; o > 0; o >>= 1) {
        if (tid < o) { s1[tid] += s1[tid + o]; s2[tid] += s2[tid + o]; }
        __syncthreads();
    }
    if (tid == 0) {
        out[0] = s1[0] / (float)N_ROWS;
        out[1 + 3 * N_ROWS] = s2[0];
    }
}

// ---------- host ----------
extern "C" void kernel_launch(void* const* d_in, const int* in_sizes, int n_in,
                              void* d_out, int out_size, void* d_ws, size_t ws_size,
                              hipStream_t stream) {
    const float* X      = (const float*)d_in[0];
    const int*   rawTgt = (const int*)d_in[1];
    const float* margin = (const float*)d_in[2];
    float* out = (float*)d_out;

    char* ws = (char*)d_ws;
    short* Xhi = (short*)ws;                                   // 16 MB
    short* Xlo = (short*)(ws + (size_t)16 * 1024 * 1024);      // 16 MB
    char* p = ws + (size_t)32 * 1024 * 1024;
    float* sumsq    = (float*)p;  p += (size_t)N_ROWS * 4;
    float* minpos   = (float*)p;  p += (size_t)N_ROWS * 4;
    ull*   maxneg   = (ull*)p;    p += (size_t)N_ROWS * 8;
    float* mn_exact = (float*)p;  p += (size_t)N_ROWS * 4;
    int*   an_cnt   = (int*)p;    p += (size_t)N_ROWS * 4;
    float* neg_sum  = (float*)p;  p += (size_t)N_ROWS * 4;
    float* loss_c   = (float*)p;  p += (size_t)N_ROWS * 4;
    int*   tgt      = (int*)p;    p += (size_t)N_ROWS * 4;
    int*   members  = (int*)p;    p += (size_t)N_ROWS * 4;
    int*   cnt      = (int*)p;    p += (size_t)NCLS * 4;
    int*   offs     = (int*)p;    p += (size_t)NCLS * 4;
    int*   pairoff  = (int*)p;    p += (size_t)NCLS * 4;
    float* simbuf   = (float*)p;  // up to 4 MB if workspace allows

    size_t used = (size_t)(p - ws);
    int simcap = (ws_size >= used + (size_t)4 * 1024 * 1024) ? (1 << 20) : 0;

    init_k<<<32, 256, 0, stream>>>(an_cnt, neg_sum, maxneg);
    bucket_k<<<1, 1024, 0, stream>>>(rawTgt, tgt, cnt, offs, pairoff, members, simcap);
    prep_k<<<N_ROWS / 4, 256, 0, stream>>>(X, Xhi, Xlo, sumsq);
    minpos_k<<<NCLS, 256, 0, stream>>>(X, members, offs, cnt, pairoff, sumsq, minpos, simbuf);
    fused_k<<<NWG2, 512, 0, stream>>>(Xhi, Xlo, tgt, margin, minpos, maxneg, an_cnt, neg_sum);
    repair_k<<<N_ROWS / 4, 256, 0, stream>>>(X, maxneg, mn_exact);
    finalize_k<<<NCLS, 256, 0, stream>>>(X, members, offs, cnt, pairoff, simbuf, sumsq,
                                         margin, mn_exact, an_cnt, neg_sum, out, loss_c);
    reduce_k<<<1, 256, 0, stream>>>(loss_c, out);
}

// Round 7
// 451.651 us; speedup vs baseline: 1.1687x; 1.1687x over previous
//
#include <hip/hip_runtime.h>
#include <math.h>

#define N_ROWS 8192
#define DIMS   1024
#define NCLS   512
#define NB     64          // 8192 / 128 blocks per dim
#define BK     32
#define NWG    (NB * (NB + 1) / 2)   // 2080 triangular blocks
#define CA     14          // class rows staged per LDS chunk (56 KB)

typedef __attribute__((ext_vector_type(8))) short bf16x8;
typedef __attribute__((ext_vector_type(4))) float f32x4;
typedef unsigned long long ull;

// ---------- helpers ----------
__device__ __forceinline__ unsigned short f2bf(float f) {
    unsigned u = __float_as_uint(f);
    u += 0x7FFFu + ((u >> 16) & 1u);   // RNE
    return (unsigned short)(u >> 16);
}
__device__ __forceinline__ float bf2f(unsigned short h) {
    return __uint_as_float(((unsigned)h) << 16);
}
// monotone float<->uint for atomic min/max
__device__ __forceinline__ unsigned enc_f(float x) {
    unsigned u = __float_as_uint(x);
    return (u & 0x80000000u) ? ~u : (u | 0x80000000u);
}
__device__ __forceinline__ float dec_f(unsigned u) {
    return (u & 0x80000000u) ? __uint_as_float(u ^ 0x80000000u) : __uint_as_float(~u);
}

__device__ __forceinline__ float dot1024(const float* __restrict__ xi,
                                         const float* __restrict__ xj) {
    const float4* u4 = (const float4*)xi;
    const float4* v4 = (const float4*)xj;
    float a0 = 0.f, a1 = 0.f, a2 = 0.f, a3 = 0.f;
#pragma unroll 8
    for (int q = 0; q < DIMS / 4; ++q) {
        float4 u = u4[q], v = v4[q];
        a0 += u.x * v.x; a1 += u.y * v.y;
        a2 += u.z * v.z; a3 += u.w * v.w;
    }
    return (a0 + a1) + (a2 + a3);
}

typedef __attribute__((address_space(1))) const void* as1_cvp;
typedef __attribute__((address_space(3))) void* as3_vp;
__device__ __forceinline__ void gl_lds16(const void* g, void* l) {
    __builtin_amdgcn_global_load_lds((as1_cvp)g, (as3_vp)l, 16, 0, 0);
}

// ---------- fused setup: block 0 = bucketing, blocks 1..2048 = prep + init ----------
__global__ __launch_bounds__(256) void setup_k(const float* __restrict__ X,
                                               const int* __restrict__ raw,
                                               short* __restrict__ Xhi,
                                               short* __restrict__ Xlo,
                                               float* __restrict__ sumsq,
                                               int* __restrict__ tgt,
                                               int* __restrict__ cnt,
                                               int* __restrict__ offs,
                                               int* __restrict__ pairoff,
                                               int* __restrict__ members,
                                               int* __restrict__ an_cnt,
                                               float* __restrict__ neg_sum,
                                               ull* __restrict__ maxneg,
                                               float* __restrict__ out,
                                               int simcap) {
    __shared__ int sflag;
    __shared__ int scnt[NCLS], soff[NCLS], spair[NCLS], scur[NCLS];
    __shared__ int schunk[16], schunkp[16];
    int tid = threadIdx.x;

    if (blockIdx.x == 0) {
        // ---- bucketing: dtype detect + conv + count + scan + scatter ----
        if (tid == 0) { sflag = 0; out[0] = 0.f; out[1 + 3 * N_ROWS] = 0.f; }
        for (int c = tid; c < NCLS; c += 256) scnt[c] = 0;
        __syncthreads();
        int any = 0;
        for (int i = tid; i < N_ROWS / 2; i += 256) any |= raw[2 * i + 1];
        if (any) atomicOr(&sflag, 1);
        __syncthreads();
        int is32 = sflag;     // nonzero odd 32-bit words => targets are int32
        for (int i = tid; i < N_ROWS; i += 256) {
            int t = is32 ? raw[i] : raw[2 * i];
            tgt[i] = t;
            if ((unsigned)t < NCLS) atomicAdd(&scnt[t], 1);
        }
        __syncthreads();
        if (tid < 16) {
            int s = 0, sp = 0;
            for (int c = tid * 32; c < tid * 32 + 32; ++c) {
                int k = scnt[c]; int kk = k < 256 ? k : 256;
                s += k; sp += kk * kk;
            }
            schunk[tid] = s; schunkp[tid] = sp;
        }
        __syncthreads();
        if (tid == 0) {
            int s = 0, sp = 0;
            for (int t = 0; t < 16; ++t) {
                int a = schunk[t], b = schunkp[t];
                schunk[t] = s; schunkp[t] = sp;
                s += a; sp += b;
            }
        }
        __syncthreads();
        if (tid < 16) {
            int s = schunk[tid], sp = schunkp[tid];
            for (int c = tid * 32; c < tid * 32 + 32; ++c) {
                int k = scnt[c]; int kk = k < 256 ? k : 256;
                soff[c] = s; scur[c] = s;
                spair[c] = (simcap > 0 && sp + kk * kk <= simcap) ? sp : -1;
                s += k; sp += kk * kk;
            }
        }
        __syncthreads();
        for (int i = tid; i < N_ROWS; i += 256) {
            int t = tgt[i];
            if ((unsigned)t < NCLS) {
                int p = atomicAdd(&scur[t], 1);
                members[p] = i;
            }
        }
        for (int c = tid; c < NCLS; c += 256) {
            cnt[c] = scnt[c]; offs[c] = soff[c]; pairoff[c] = spair[c];
        }
    } else {
        // ---- prep: fp32 -> bf16 hi/lo split + row sumsq (wave per row) + init ----
        int rowbase = (blockIdx.x - 1) * 4;
        int row  = rowbase + (tid >> 6);
        int lane = tid & 63;
        const float4* xr = (const float4*)(X + (size_t)row * DIMS);
        short4* oh = (short4*)(Xhi + (size_t)row * DIMS);
        short4* ol = (short4*)(Xlo + (size_t)row * DIMS);
        float ss = 0.f;
#pragma unroll
        for (int t = 0; t < 4; ++t) {
            float4 v = xr[lane + 64 * t];
            ss += v.x * v.x + v.y * v.y + v.z * v.z + v.w * v.w;
            short4 h, l;
            unsigned short hx = f2bf(v.x); h.x = (short)hx; l.x = (short)f2bf(v.x - bf2f(hx));
            unsigned short hy = f2bf(v.y); h.y = (short)hy; l.y = (short)f2bf(v.y - bf2f(hy));
            unsigned short hz = f2bf(v.z); h.z = (short)hz; l.z = (short)f2bf(v.z - bf2f(hz));
            unsigned short hw = f2bf(v.w); h.w = (short)hw; l.w = (short)f2bf(v.w - bf2f(hw));
            oh[lane + 64 * t] = h;
            ol[lane + 64 * t] = l;
        }
#pragma unroll
        for (int off = 1; off < 64; off <<= 1) ss += __shfl_xor(ss, off);
        if (lane == 0) sumsq[row] = ss;
        if (tid < 4) {
            int r = rowbase + tid;
            an_cnt[r] = 0; neg_sum[r] = 0.f;
            maxneg[r] = ((ull)enc_f(-1e9f)) << 32;
        }
    }
}

// ---------- min_pos: LDS-staged class grams (rows read once, not per pair) ----------
__global__ __launch_bounds__(256) void minpos_k(const float* __restrict__ X,
                                                const int* __restrict__ members,
                                                const int* __restrict__ offs,
                                                const int* __restrict__ cnt,
                                                const int* __restrict__ pairoff,
                                                const float* __restrict__ sumsq,
                                                float* __restrict__ minpos,
                                                float* __restrict__ simbuf) {
    __shared__ __align__(16) float srows[CA][DIMS];   // 56 KB
    __shared__ unsigned smin[256];
    int c = blockIdx.x, tid = threadIdx.x;
    int wave = tid >> 6, lane = tid & 63;
    int k = cnt[c], off = offs[c], spo = pairoff[c];
    smin[tid] = enc_f(1e9f);
    int kk = k < 256 ? k : 256;
    __syncthreads();
    for (int a0 = 0; a0 < kk; a0 += CA) {
        int na = (kk - a0 < CA) ? (kk - a0) : CA;
        // cooperative stage: 256 threads cover one row (256 float4) per step
        for (int idx = tid; idx < na * 256; idx += 256) {
            int r = idx >> 8, c4 = idx & 255;
            int i = members[off + a0 + r];
            ((float4*)&srows[r][0])[c4] = ((const float4*)(X + (size_t)i * DIMS))[c4];
        }
        __syncthreads();
        // wave-per-b: row j in registers, dot vs staged rows from LDS
        for (int b = wave; b < kk; b += 4) {
            int j = members[off + b];
            const float4* xj = (const float4*)(X + (size_t)j * DIMS);
            float4 rj[4];
#pragma unroll
            for (int t = 0; t < 4; ++t) rj[t] = xj[lane + 64 * t];
            for (int a = 0; a < na; ++a) {
                int i = members[off + a0 + a];
                float p0 = 0.f, p1 = 0.f, p2 = 0.f, p3 = 0.f;
#pragma unroll
                for (int t = 0; t < 4; ++t) {
                    float4 u = ((const float4*)&srows[a][0])[lane + 64 * t];
                    p0 += u.x * rj[t].x; p1 += u.y * rj[t].y;
                    p2 += u.z * rj[t].z; p3 += u.w * rj[t].w;
                }
                float s = (p0 + p1) + (p2 + p3);
#pragma unroll
                for (int o = 1; o < 64; o <<= 1) s += __shfl_xor(s, o);
                if (i == j) s = sumsq[i];
                if (lane == 0) {
                    if (spo >= 0) simbuf[spo + (a0 + a) * kk + b] = s;
                    if (s < 1.0f) atomicMin(&smin[a0 + a], enc_f(s));
                }
            }
        }
        __syncthreads();   // srows reuse + smin visibility
    }
    for (int a = tid; a < kk; a += 256) minpos[members[off + a]] = dec_f(smin[a]);
}

// ---------- main fused GEMM (hi/lo bf16 x3, symmetric) + negative epilogue ----------
__global__ __launch_bounds__(256, 4) void fused_k(const short* __restrict__ Xhi,
                                                  const short* __restrict__ Xlo,
                                                  const int* __restrict__ tgt,
                                                  const float* __restrict__ margin,
                                                  const float* __restrict__ minpos,
                                                  ull* __restrict__ maxneg,
                                                  int* __restrict__ an_cnt,
                                                  float* __restrict__ neg_sum) {
    __shared__ __align__(16) short sAh[128][BK];
    __shared__ __align__(16) short sAl[128][BK];
    __shared__ __align__(16) short sBh[128][BK];
    __shared__ __align__(16) short sBl[128][BK];

    // bijective XCD-aware swizzle (nwg = 2080 = 8*260, r = 0)
    int orig = blockIdx.x;
    int xcd = orig & 7;
    int wgid = xcd * (NWG >> 3) + (orig >> 3);

    // triangular block decode (uniform scalar loop)
    int rem = wgid, by = 0;
    while (rem >= NB - by) { rem -= NB - by; ++by; }
    int bx = by + rem;
    bool mirror = (bx != by);
    int row0 = by * 128, col0 = bx * 128;

    int tid = threadIdx.x, lane = tid & 63, wave = tid >> 6;
    int wr = wave >> 1, wc = wave & 1;
    int l15 = lane & 15, l4 = lane >> 4;

    // wave w stages buffer w: 0=Ah 1=Al 2=Bh 3=Bl (linear LDS, DMA)
    const short* gsrc = (wave & 1) ? Xlo : Xhi;
    int base0 = (wave & 2) ? col0 : row0;
    short (*lbuf)[BK] = (wave == 0) ? sAh : (wave == 1) ? sAl : (wave == 2) ? sBh : sBl;
    int lrow = lane >> 2, lcc = (lane & 3) * 8;
    const short* gp = gsrc + (size_t)(base0 + lrow) * DIMS + lcc;

    f32x4 acc[4][4] = {};

    for (int k0 = 0; k0 < DIMS; k0 += BK) {
        if (k0) __syncthreads();
#pragma unroll
        for (int t = 0; t < 8; ++t) {
            gl_lds16(gp + (size_t)(t * 16) * DIMS + k0, &lbuf[t * 16][0]);
        }
        __syncthreads();

        bf16x8 bh[4], bl[4];
#pragma unroll
        for (int n = 0; n < 4; ++n) {
            int rb = wc * 64 + n * 16 + l15;
            bh[n] = *(const bf16x8*)&sBh[rb][l4 * 8];
            bl[n] = *(const bf16x8*)&sBl[rb][l4 * 8];
        }
#pragma unroll
        for (int m = 0; m < 4; ++m) {
            int ra = wr * 64 + m * 16 + l15;
            bf16x8 ah = *(const bf16x8*)&sAh[ra][l4 * 8];
            bf16x8 al = *(const bf16x8*)&sAl[ra][l4 * 8];
#pragma unroll
            for (int n = 0; n < 4; ++n) {
                acc[m][n] = __builtin_amdgcn_mfma_f32_16x16x32_bf16(ah, bh[n], acc[m][n], 0, 0, 0);
                acc[m][n] = __builtin_amdgcn_mfma_f32_16x16x32_bf16(ah, bl[n], acc[m][n], 0, 0, 0);
                acc[m][n] = __builtin_amdgcn_mfma_f32_16x16x32_bf16(al, bh[n], acc[m][n], 0, 0, 0);
            }
        }
    }

    // ---- epilogue: C/D layout col=lane&15, row=(lane>>4)*4+r ----
    int tcol[4]; float mcol[4], pcol[4];
#pragma unroll
    for (int n = 0; n < 4; ++n) {
        int gc = col0 + wc * 64 + n * 16 + l15;
        tcol[n] = tgt[gc];
        mcol[n] = mirror ? margin[gc] : 0.f;
        pcol[n] = mirror ? minpos[gc] : 0.f;
    }
    ull  cmx[4] = {0, 0, 0, 0};
    float cns[4] = {0, 0, 0, 0};
    int  cct[4] = {0, 0, 0, 0};

#pragma unroll
    for (int m = 0; m < 4; ++m) {
#pragma unroll
        for (int r = 0; r < 4; ++r) {
            int grow = row0 + wr * 64 + m * 16 + l4 * 4 + r;
            int trow = tgt[grow];
            float mg = margin[grow], mp = minpos[grow];
            ull rmx = 0; float rns = 0.f; int rct = 0;
#pragma unroll
            for (int n = 0; n < 4; ++n) {
                float s = acc[m][n][r];
                if (trow != tcol[n]) {
                    float e = __expf(10.f * s - 5.f);
                    int gc = col0 + wc * 64 + n * 16 + l15;
                    ull pk = (((ull)enc_f(s)) << 32) | (unsigned)gc;
                    rmx = rmx > pk ? rmx : pk;
                    if (s + mg - mp > 0.f) { rct++; rns += e; }
                    if (mirror) {
                        ull pk2 = (((ull)enc_f(s)) << 32) | (unsigned)grow;
                        cmx[n] = cmx[n] > pk2 ? cmx[n] : pk2;
                        if (s + mcol[n] - pcol[n] > 0.f) { cct[n]++; cns[n] += e; }
                    }
                }
            }
#pragma unroll
            for (int off = 1; off < 16; off <<= 1) {
                ull o = __shfl_xor(rmx, off); rmx = rmx > o ? rmx : o;
                rns += __shfl_xor(rns, off);
                rct += __shfl_xor(rct, off);
            }
            if (l15 == 0) {
                atomicMax(&maxneg[grow], rmx);
                if (rct) { atomicAdd(&an_cnt[grow], rct); atomicAdd(&neg_sum[grow], rns); }
            }
        }
    }
    if (mirror) {
#pragma unroll
        for (int n = 0; n < 4; ++n) {
#pragma unroll
            for (int off = 16; off < 64; off <<= 1) {
                ull o = __shfl_xor(cmx[n], off); cmx[n] = cmx[n] > o ? cmx[n] : o;
                cns[n] += __shfl_xor(cns[n], off);
                cct[n] += __shfl_xor(cct[n], off);
            }
            if (lane < 16) {
                int gc = col0 + wc * 64 + n * 16 + l15;
                atomicMax(&maxneg[gc], cmx[n]);
                if (cct[n]) { atomicAdd(&an_cnt[gc], cct[n]); atomicAdd(&neg_sum[gc], cns[n]); }
            }
        }
    }
}

// ---------- positive path + argmax repair + outputs + scalar reduction ----------
__global__ __launch_bounds__(256) void finalize_k(const float* __restrict__ X,
                                                  const int* __restrict__ members,
                                                  const int* __restrict__ offs,
                                                  const int* __restrict__ cnt,
                                                  const int* __restrict__ pairoff,
                                                  const float* __restrict__ simbuf,
                                                  const float* __restrict__ sumsq,
                                                  const float* __restrict__ margin,
                                                  const ull* __restrict__ maxneg,
                                                  const int* __restrict__ an_cnt,
                                                  const float* __restrict__ neg_sum,
                                                  float* __restrict__ out) {
    __shared__ int sap[256];
    __shared__ float sps[256];
    __shared__ float smn[256], smg[256];
    __shared__ float sred[8];
    int c = blockIdx.x, tid = threadIdx.x;
    int wave = tid >> 6, lane = tid & 63;
    int k = cnt[c], off = offs[c], spo = pairoff[c];
    int kk = k < 256 ? k : 256;
    sap[tid] = 0; sps[tid] = 0.f;

    // exact fp32 max_neg at the GEMM argmax (wave per member)
    for (int a = wave; a < kk; a += 4) {
        int i = members[off + a];
        ull pm = maxneg[i];
        float mn = -1e9f;
        if ((unsigned)(pm >> 32) != enc_f(-1e9f)) {
            int col = (int)(pm & 0xFFFFFFFFu);
            const float4* xi = (const float4*)(X + (size_t)i * DIMS);
            const float4* xj = (const float4*)(X + (size_t)col * DIMS);
            float a0 = 0.f, a1 = 0.f, a2 = 0.f, a3 = 0.f;
#pragma unroll
            for (int t = 0; t < 4; ++t) {
                float4 u = xi[lane + 64 * t], v = xj[lane + 64 * t];
                a0 += u.x * v.x; a1 += u.y * v.y;
                a2 += u.z * v.z; a3 += u.w * v.w;
            }
            float s = (a0 + a1) + (a2 + a3);
#pragma unroll
            for (int o = 1; o < 64; o <<= 1) s += __shfl_xor(s, o);
            mn = s;
        }
        if (lane == 0) { smn[a] = mn; smg[a] = margin[i]; }
    }
    __syncthreads();

    for (int p = tid; p < kk * kk; p += 256) {
        int a = p / kk;
        float s;
        if (spo >= 0) {
            s = simbuf[spo + p];
        } else {
            int b = p - a * kk;
            int i = members[off + a], j = members[off + b];
            s = (i == j) ? sumsq[i]
                         : dot1024(X + (size_t)i * DIMS, X + (size_t)j * DIMS);
        }
        if (s < 1.0f && (smn[a] - s + smg[a] > 0.f)) {
            atomicAdd(&sap[a], 1);
            atomicAdd(&sps[a], __expf(-2.f * s + 1.f));
        }
    }
    __syncthreads();

    float bl = 0.f, bt = 0.f;
    for (int a = tid; a < kk; a += 256) {
        int i = members[off + a];
        int ap = sap[a];
        int an = an_cnt[i];
        bool valid = (ap > 0) && (an > 0);
        float pl = log1pf(sps[a]);
        float nl = 0.2f * log1pf(neg_sum[i]);
        out[1 + i]              = valid ? 1.f : 0.f;
        out[1 + N_ROWS + i]     = valid ? (float)ap : 0.f;
        out[1 + 2 * N_ROWS + i] = valid ? (float)an : 0.f;
        bl += valid ? (pl + nl) : 0.f;
        bt += valid ? (float)(ap + an) : 0.f;
    }
#pragma unroll
    for (int o = 1; o < 64; o <<= 1) {
        bl += __shfl_xor(bl, o);
        bt += __shfl_xor(bt, o);
    }
    if (lane == 0) { sred[wave] = bl; sred[4 + wave] = bt; }
    __syncthreads();
    if (tid == 0) {
        float L = sred[0] + sred[1] + sred[2] + sred[3];
        float T = sred[4] + sred[5] + sred[6] + sred[7];
        atomicAdd(&out[0], L / (float)N_ROWS);
        atomicAdd(&out[1 + 3 * N_ROWS], T);
    }
}

// ---------- host ----------
extern "C" void kernel_launch(void* const* d_in, const int* in_sizes, int n_in,
                              void* d_out, int out_size, void* d_ws, size_t ws_size,
                              hipStream_t stream) {
    const float* X      = (const float*)d_in[0];
    const int*   rawTgt = (const int*)d_in[1];
    const float* margin = (const float*)d_in[2];
    float* out = (float*)d_out;

    char* ws = (char*)d_ws;
    short* Xhi = (short*)ws;                                   // 16 MB
    short* Xlo = (short*)(ws + (size_t)16 * 1024 * 1024);      // 16 MB
    char* p = ws + (size_t)32 * 1024 * 1024;
    float* sumsq    = (float*)p;  p += (size_t)N_ROWS * 4;
    float* minpos   = (float*)p;  p += (size_t)N_ROWS * 4;
    ull*   maxneg   = (ull*)p;    p += (size_t)N_ROWS * 8;
    int*   an_cnt   = (int*)p;    p += (size_t)N_ROWS * 4;
    float* neg_sum  = (float*)p;  p += (size_t)N_ROWS * 4;
    int*   tgt      = (int*)p;    p += (size_t)N_ROWS * 4;
    int*   members  = (int*)p;    p += (size_t)N_ROWS * 4;
    int*   cnt      = (int*)p;    p += (size_t)NCLS * 4;
    int*   offs     = (int*)p;    p += (size_t)NCLS * 4;
    int*   pairoff  = (int*)p;    p += (size_t)NCLS * 4;
    float* simbuf   = (float*)p;  // up to 4 MB if workspace allows

    size_t used = (size_t)(p - ws);
    int simcap = (ws_size >= used + (size_t)4 * 1024 * 1024) ? (1 << 20) : 0;

    setup_k<<<1 + N_ROWS / 4, 256, 0, stream>>>(X, rawTgt, Xhi, Xlo, sumsq, tgt, cnt, offs,
                                                pairoff, members, an_cnt, neg_sum, maxneg,
                                                out, simcap);
    minpos_k<<<NCLS, 256, 0, stream>>>(X, members, offs, cnt, pairoff, sumsq, minpos, simbuf);
    fused_k<<<NWG, 256, 0, stream>>>(Xhi, Xlo, tgt, margin, minpos, maxneg, an_cnt, neg_sum);
    finalize_k<<<NCLS, 256, 0, stream>>>(X, members, offs, cnt, pairoff, simbuf, sumsq,
                                         margin, maxneg, an_cnt, neg_sum, out);
}